// Round 14
// baseline (993.571 us; speedup 1.0000x reference)
//
#include <hip/hip_runtime.h>

// Problem constants (fixed by setup_inputs)
constexpr int B   = 16;
constexpr int N   = 16384;
constexpr int M   = 256;   // n_centers
constexpr int K   = 32;    // knn
constexpr int EMB = 256;

// Exact (non-contracted) squared distance in the reference's association
// order: ((dx*dx + dy*dy) + dz*dz). Must be bit-identical to XLA CPU so the
// FPS argmax / kNN top-k selections match.
__device__ __forceinline__ float sqdist(float px, float py, float pz,
                                        float cx, float cy, float cz) {
  float dx = __fsub_rn(px, cx);
  float dy = __fsub_rn(py, cy);
  float dz = __fsub_rn(pz, cz);
  return __fadd_rn(__fadd_rn(__fmul_rn(dx, dx), __fmul_rn(dy, dy)),
                   __fmul_rn(dz, dz));
}

// ---------------------------------------------------------------- FPS ------
// Empirical law (r5-r13): ANY loop-carried per-thread bulk state spills
// (VGPR grants 36-88 across every hint); scalar LDS loses on instruction
// count (r12); spill RMW serializes (r13). v6: ALL bulk state in LDS,
// accessed ONLY as b128 chunks in the canonical conflict-free pattern
// chunk[c*1024+tid] (lane-contiguous 16B). Register loop state = 4 floats.
//   LDS: coords pts 0-7 (6 chunks, 96KB) + dist pts 0-11 (3 chunks, 48KB)
//   L2-streamed: coords pts 8-15 (6 global b128/iter)
//   regs: dist pts 12-15
// Per iter/CU: LDS 192KB/128Bcyc~1500cyc || VMEM 96KB/56Bcyc~1750cyc ||
// VALU ~1440cyc, + ~500cyc tail -> ~0.95us/iter.
constexpr int FT = 1024;
constexpr int FW = FT / 64;       // 16 waves

__global__ __launch_bounds__(FT) void fps_kernel(
    const float* __restrict__ xyz, float* __restrict__ centers) {
  const int b = blockIdx.x;
  const int tid = threadIdx.x;
  const float* base = xyz + (size_t)b * N * 3;
  const float4* b4 = (const float4*)base;   // 16B-aligned

  __shared__ float4 s_co[6 * FT];   // 96 KB: coords of pts j=0..7 per thread
  __shared__ float4 s_dA[3 * FT];   // 48 KB: dist of pts j=0..11 per thread
  __shared__ float s_pv[2][FW];
  __shared__ int s_pn[2][FW];

  const int f0 = tid * 12;          // first global float4 of this thread
#pragma unroll
  for (int c = 0; c < 6; ++c) s_co[c * FT + tid] = b4[f0 + c];
  const float inf = __builtin_inff();
#pragma unroll
  for (int c = 0; c < 3; ++c) s_dA[c * FT + tid] = make_float4(inf, inf, inf, inf);
  float ds12 = inf, ds13 = inf, ds14 = inf, ds15 = inf;

  // deterministic start: carry = point 0
  float cx = base[0], cy = base[1], cz = base[2];
  __syncthreads();

  for (int it = 0; it < M; ++it) {
    if (tid == 0) {  // emit current carry (matches lax.scan semantics)
      float* co = centers + ((size_t)b * M + it) * 3;
      co[0] = cx; co[1] = cy; co[2] = cz;
    }
    const int p = it & 1;

    float bv = -1.0f;
    int bj = 0;

    // strict >: ascending j within the thread -> lowest global idx wins ties
#define FPS_UPD(D, J, X, Y, Z) {                           \
    float dx = __fsub_rn((X), cx);                         \
    float dy = __fsub_rn((Y), cy);                         \
    float dz = __fsub_rn((Z), cz);                         \
    float dd = __fadd_rn(__fadd_rn(__fmul_rn(dx, dx),      \
                                   __fmul_rn(dy, dy)),     \
                         __fmul_rn(dz, dz));               \
    float nd = fminf(D, dd);                               \
    D = nd;                                                \
    bool g = nd > bv;                                      \
    bv = g ? nd : bv;                                      \
    bj = g ? (J) : bj; }

#define FPS_G4(qa, qb, qc, D0, D1, D2, D3, JB)             \
    FPS_UPD(D0, (JB) + 0, qa.x, qa.y, qa.z)                \
    FPS_UPD(D1, (JB) + 1, qa.w, qb.x, qb.y)                \
    FPS_UPD(D2, (JB) + 2, qb.z, qb.w, qc.x)                \
    FPS_UPD(D3, (JB) + 3, qc.y, qc.z, qc.w)

    // issue first half of the streamed coords (consumed in group 2)
    float4 g0 = b4[f0 + 6], g1 = b4[f0 + 7], g2 = b4[f0 + 8];

    {  // group 0: pts 0..3 (LDS coords chunks 0-2, LDS dist chunk 0)
      float4 qa = s_co[0 * FT + tid];
      float4 qb = s_co[1 * FT + tid];
      float4 qc = s_co[2 * FT + tid];
      float4 dq = s_dA[0 * FT + tid];
      FPS_G4(qa, qb, qc, dq.x, dq.y, dq.z, dq.w, 0)
      s_dA[0 * FT + tid] = dq;
    }
    // issue second half of the streamed coords (consumed in group 3)
    float4 g3 = b4[f0 + 9], g4 = b4[f0 + 10], g5 = b4[f0 + 11];
    {  // group 1: pts 4..7 (LDS coords chunks 3-5, LDS dist chunk 1)
      float4 qa = s_co[3 * FT + tid];
      float4 qb = s_co[4 * FT + tid];
      float4 qc = s_co[5 * FT + tid];
      float4 dq = s_dA[1 * FT + tid];
      FPS_G4(qa, qb, qc, dq.x, dq.y, dq.z, dq.w, 4)
      s_dA[1 * FT + tid] = dq;
    }
    {  // group 2: pts 8..11 (streamed coords g0-g2, LDS dist chunk 2)
      float4 dq = s_dA[2 * FT + tid];
      FPS_G4(g0, g1, g2, dq.x, dq.y, dq.z, dq.w, 8)
      s_dA[2 * FT + tid] = dq;
    }
    // group 3: pts 12..15 (streamed coords g3-g5, register dists)
    FPS_G4(g3, g4, g5, ds12, ds13, ds14, ds15, 12)
#undef FPS_G4
#undef FPS_UPD

    int bn = (tid << 4) + bj;   // global point index (blocked mapping)

    // wave-level argmax, tie -> lowest global index
#pragma unroll
    for (int mm = 32; mm >= 1; mm >>= 1) {
      float ov = __shfl_xor(bv, mm, 64);
      int on = __shfl_xor(bn, mm, 64);
      if (ov > bv || (ov == bv && on < bn)) { bv = ov; bn = on; }
    }
    if ((tid & 63) == 0) { s_pv[p][tid >> 6] = bv; s_pn[p][tid >> 6] = bn; }
    __syncthreads();

    // every thread reduces the 16 wave partials (broadcast LDS reads)
    float v = s_pv[p][0];
    int n = s_pn[p][0];
#pragma unroll
    for (int w = 1; w < FW; ++w) {
      float ov = s_pv[p][w];
      int on = s_pn[p][w];
      if (ov > v || (ov == v && on < n)) { v = ov; n = on; }
    }
    // broadcast-load next center (uniform address -> one fetch)
    cx = base[(size_t)n * 3 + 0];
    cy = base[(size_t)n * 3 + 1];
    cz = base[(size_t)n * 3 + 2];
    // no second barrier: parity-double-buffered partials make it race-free
  }
}

// ---------------------------------------------------------------- kNN ------
// Bucket-select on float bit prefixes (monotone for d >= 0). Only the SET of
// 32 nearest matters (max-pool later), so slots are written in arbitrary
// order; boundary-bucket ties resolved exactly by (bits, index).
constexpr int KT = 256;
constexpr int CAP = 512;
constexpr int NBUCKET = 1024;

__global__ __launch_bounds__(KT) void knn_kernel(
    const float* __restrict__ xyz, const float* __restrict__ centers,
    float* __restrict__ patches) {
  const int blk = blockIdx.x;      // b*M + m
  const int b = blk >> 8;          // M == 256
  const int tid = threadIdx.x;
  const float* base = xyz + (size_t)b * N * 3;

  __shared__ int hist[NBUCKET];
  __shared__ unsigned cb[CAP];
  __shared__ int ci[CAP];
  __shared__ int s_nin, s_ncand, s_tb;
  __shared__ int s_wsum[KT / 64];
  __shared__ float s_cc[3];

  if (tid == 0) {
    const float* c = centers + (size_t)blk * 3;
    s_cc[0] = c[0]; s_cc[1] = c[1]; s_cc[2] = c[2];
    s_nin = 0; s_ncand = 0;
  }
  for (int i = tid; i < NBUCKET; i += KT) hist[i] = 0;
  __syncthreads();

  const float cx = s_cc[0], cy = s_cc[1], cz = s_cc[2];

  // pass 1: histogram of 10-bit float prefixes
  for (int n = tid; n < N; n += KT) {
    float d = sqdist(base[n * 3], base[n * 3 + 1], base[n * 3 + 2], cx, cy, cz);
    atomicAdd(&hist[__float_as_uint(d) >> 21], 1);
  }
  __syncthreads();

  // block scan over 1024 buckets (4 per thread) to find threshold bucket
  int h0[4];
  int loc = 0;
#pragma unroll
  for (int i = 0; i < 4; ++i) { h0[i] = hist[tid * 4 + i]; loc += h0[i]; }
  int lane = tid & 63, wid = tid >> 6;
  int scan = loc;
  for (int off = 1; off < 64; off <<= 1) {
    int o = __shfl_up(scan, off, 64);
    if (lane >= off) scan += o;
  }
  if (lane == 63) s_wsum[wid] = scan;
  __syncthreads();
  int woff = 0;
  for (int w = 0; w < wid; ++w) woff += s_wsum[w];
  int c0 = woff + scan - loc;  // count strictly below this thread's buckets
#pragma unroll
  for (int i = 0; i < 4; ++i) {
    int c1 = c0 + h0[i];
    if (c0 < K && c1 >= K) s_tb = tid * 4 + i;  // unique crossing bucket
    c0 = c1;
  }
  __syncthreads();
  const int tb = s_tb;
  const unsigned lo = (unsigned)tb << 21;
  const unsigned hi = (unsigned)(tb + 1) << 21;

  // pass 2: emit sure-ins, collect boundary candidates
  for (int n = tid; n < N; n += KT) {
    float x = base[n * 3], y = base[n * 3 + 1], z = base[n * 3 + 2];
    float d = sqdist(x, y, z, cx, cy, cz);
    unsigned bits = __float_as_uint(d);
    if (bits < lo) {
      int pos = atomicAdd(&s_nin, 1);
      float* p = patches + ((size_t)blk * K + pos) * 3;
      p[0] = __fsub_rn(x, cx); p[1] = __fsub_rn(y, cy); p[2] = __fsub_rn(z, cz);
    } else if (bits < hi) {
      int q = atomicAdd(&s_ncand, 1);
      if (q < CAP) { cb[q] = bits; ci[q] = n; }
    }
  }
  __syncthreads();

  // exact rank-select among boundary candidates: (bits, idx) lexicographic
  const int nin = s_nin;
  const int ncand = min(s_ncand, CAP);
  const int nsel = K - nin;
  for (int j = tid; j < ncand; j += KT) {
    unsigned bj = cb[j];
    int ij = ci[j];
    int rank = 0;
    for (int i2 = 0; i2 < ncand; ++i2) {
      unsigned bv = cb[i2];
      int iv = ci[i2];
      rank += (bv < bj || (bv == bj && iv < ij)) ? 1 : 0;
    }
    if (rank < nsel) {
      float x = base[ij * 3], y = base[ij * 3 + 1], z = base[ij * 3 + 2];
      float* p = patches + ((size_t)blk * K + nin + rank) * 3;
      p[0] = __fsub_rn(x, cx); p[1] = __fsub_rn(y, cy); p[2] = __fsub_rn(z, cz);
    }
  }
}

// ---------------------------------------------------------------- MLP ------
// One block per patch. h1/h2 staged in LDS, rows XOR-swizzled so the b128
// writes are conflict-light; reads are uniform-address broadcasts.
constexpr int MT = 128;

__global__ __launch_bounds__(MT) void mlp_kernel(
    const float* __restrict__ patches,
    const float* __restrict__ W1, const float* __restrict__ b1,
    const float* __restrict__ g1, const float* __restrict__ bt1,
    const float* __restrict__ W2, const float* __restrict__ b2,
    const float* __restrict__ g2, const float* __restrict__ bt2,
    const float* __restrict__ W3, const float* __restrict__ b3,
    const float* __restrict__ g3, const float* __restrict__ bt3,
    float* __restrict__ tokens) {
  const int pm = blockIdx.x;
  const int tid = threadIdx.x;
  __shared__ float xs[3][K];
  __shared__ float h1s[64 * K];
  __shared__ float h2s[128 * K];
  __shared__ float pms[2][EMB];

  const float* patch = patches + (size_t)pm * (K * 3);
  if (tid < 96) xs[tid % 3][tid / 3] = patch[tid];
  __syncthreads();

  const int cg = tid & 63;
  const int half = tid >> 6;
  const int pt0 = half * 16;
  const float rs = 1.0f / sqrtf(1.0f + 1e-5f);

  // L1: 3 -> 64
  {
    const int c = cg;
    const float w0 = W1[c], w1 = W1[64 + c], w2 = W1[128 + c];
    const float bb = b1[c];
    const float sc = g1[c] * rs, be = bt1[c];
    float o[16];
#pragma unroll
    for (int p = 0; p < 16; ++p) {
      int pt = pt0 + p;
      float a = xs[0][pt] * w0 + xs[1][pt] * w1 + xs[2][pt] * w2 + bb;
      o[p] = fmaxf(a * sc + be, 0.0f);
    }
    const int so = (c & 7) << 2;
#pragma unroll
    for (int p4 = 0; p4 < 16; p4 += 4) {
      *(float4*)&h1s[c * K + ((pt0 + p4) ^ so)] =
          make_float4(o[p4], o[p4 + 1], o[p4 + 2], o[p4 + 3]);
    }
  }
  __syncthreads();

  // L2: 64 -> 128, c-tile 2 x pt-tile 16
  {
    const int c = cg * 2;
    float acc0[16], acc1[16];
    const float bb0 = b2[c], bb1 = b2[c + 1];
#pragma unroll
    for (int p = 0; p < 16; ++p) { acc0[p] = bb0; acc1[p] = bb1; }
    for (int k = 0; k < 64; ++k) {
      const float2 w = *(const float2*)(W2 + k * 128 + c);
      const int so = (k & 7) << 2;
      float4 x0 = *(const float4*)&h1s[k * K + ((pt0 + 0) ^ so)];
      float4 x1 = *(const float4*)&h1s[k * K + ((pt0 + 4) ^ so)];
      float4 x2 = *(const float4*)&h1s[k * K + ((pt0 + 8) ^ so)];
      float4 x3 = *(const float4*)&h1s[k * K + ((pt0 + 12) ^ so)];
      float xv[16] = {x0.x, x0.y, x0.z, x0.w, x1.x, x1.y, x1.z, x1.w,
                      x2.x, x2.y, x2.z, x2.w, x3.x, x3.y, x3.z, x3.w};
#pragma unroll
      for (int p = 0; p < 16; ++p) {
        acc0[p] += xv[p] * w.x;
        acc1[p] += xv[p] * w.y;
      }
    }
    const float sc0 = g2[c] * rs, be0 = bt2[c];
    const float sc1 = g2[c + 1] * rs, be1 = bt2[c + 1];
    float o0[16], o1[16];
#pragma unroll
    for (int p = 0; p < 16; ++p) {
      o0[p] = fmaxf(acc0[p] * sc0 + be0, 0.0f);
      o1[p] = fmaxf(acc1[p] * sc1 + be1, 0.0f);
    }
    const int soa = (c & 7) << 2, sob = ((c + 1) & 7) << 2;
#pragma unroll
    for (int p4 = 0; p4 < 16; p4 += 4) {
      *(float4*)&h2s[c * K + ((pt0 + p4) ^ soa)] =
          make_float4(o0[p4], o0[p4 + 1], o0[p4 + 2], o0[p4 + 3]);
      *(float4*)&h2s[(c + 1) * K + ((pt0 + p4) ^ sob)] =
          make_float4(o1[p4], o1[p4 + 1], o1[p4 + 2], o1[p4 + 3]);
    }
  }
  __syncthreads();

  // L3: 128 -> 256, c-tile 4 x pt-tile 16, fused BN+ReLU+max over its pts
  {
    const int c = cg * 4;
    float acc[4][16];
#pragma unroll
    for (int i = 0; i < 4; ++i) {
      const float bb = b3[c + i];
#pragma unroll
      for (int p = 0; p < 16; ++p) acc[i][p] = bb;
    }
    for (int k = 0; k < 128; ++k) {
      const float4 w = *(const float4*)(W3 + (size_t)k * 256 + c);
      const int so = (k & 7) << 2;
      float4 x0 = *(const float4*)&h2s[k * K + ((pt0 + 0) ^ so)];
      float4 x1 = *(const float4*)&h2s[k * K + ((pt0 + 4) ^ so)];
      float4 x2 = *(const float4*)&h2s[k * K + ((pt0 + 8) ^ so)];
      float4 x3 = *(const float4*)&h2s[k * K + ((pt0 + 12) ^ so)];
      float xv[16] = {x0.x, x0.y, x0.z, x0.w, x1.x, x1.y, x1.z, x1.w,
                      x2.x, x2.y, x2.z, x2.w, x3.x, x3.y, x3.z, x3.w};
#pragma unroll
      for (int p = 0; p < 16; ++p) {
        acc[0][p] += xv[p] * w.x;
        acc[1][p] += xv[p] * w.y;
        acc[2][p] += xv[p] * w.z;
        acc[3][p] += xv[p] * w.w;
      }
    }
#pragma unroll
    for (int i = 0; i < 4; ++i) {
      const float sc = g3[c + i] * rs, be = bt3[c + i];
      float mx = 0.0f;  // ReLU outputs are >= 0, so 0 is a safe identity
#pragma unroll
      for (int p = 0; p < 16; ++p)
        mx = fmaxf(mx, fmaxf(acc[i][p] * sc + be, 0.0f));
      pms[half][c + i] = mx;
    }
  }
  __syncthreads();

  {
    const int c2 = tid * 2;
    float* to = tokens + (size_t)pm * EMB;
    to[c2] = fmaxf(pms[0][c2], pms[1][c2]);
    to[c2 + 1] = fmaxf(pms[0][c2 + 1], pms[1][c2 + 1]);
  }
}

// ------------------------------------------------------------- launcher ----
extern "C" void kernel_launch(void* const* d_in, const int* in_sizes, int n_in,
                              void* d_out, int out_size, void* d_ws,
                              size_t ws_size, hipStream_t stream) {
  const float* xyz = (const float*)d_in[0];
  const float* W1 = (const float*)d_in[1];
  const float* b1 = (const float*)d_in[2];
  const float* g1 = (const float*)d_in[3];
  const float* bt1 = (const float*)d_in[4];
  const float* W2 = (const float*)d_in[5];
  const float* b2 = (const float*)d_in[6];
  const float* g2 = (const float*)d_in[7];
  const float* bt2 = (const float*)d_in[8];
  const float* W3 = (const float*)d_in[9];
  const float* b3 = (const float*)d_in[10];
  const float* g3 = (const float*)d_in[11];
  const float* bt3 = (const float*)d_in[12];

  float* tokens = (float*)d_out;                       // (B,M,EMB)
  float* centers = tokens + (size_t)B * M * EMB;       // (B,M,3)
  float* patches = (float*)d_ws;                       // (B*M, K, 3)

  fps_kernel<<<B, FT, 0, stream>>>(xyz, centers);
  knn_kernel<<<B * M, KT, 0, stream>>>(xyz, centers, patches);
  mlp_kernel<<<B * M, MT, 0, stream>>>(patches, W1, b1, g1, bt1, W2, b2, g2,
                                       bt2, W3, b3, g3, bt3, tokens);
}

// Round 15
// 835.662 us; speedup vs baseline: 1.1890x; 1.1890x over previous
//
#include <hip/hip_runtime.h>

// Problem constants (fixed by setup_inputs)
constexpr int B   = 16;
constexpr int N   = 16384;
constexpr int M   = 256;   // n_centers
constexpr int K   = 32;    // knn
constexpr int EMB = 256;

// Exact (non-contracted) squared distance in the reference's association
// order: ((dx*dx + dy*dy) + dz*dz). Must be bit-identical to XLA CPU so the
// FPS argmax / kNN top-k selections match.
__device__ __forceinline__ float sqdist(float px, float py, float pz,
                                        float cx, float cy, float cz) {
  float dx = __fsub_rn(px, cx);
  float dy = __fsub_rn(py, cy);
  float dz = __fsub_rn(pz, cz);
  return __fadd_rn(__fadd_rn(__fmul_rn(dx, dx), __fmul_rn(dy, dy)),
                   __fmul_rn(dz, dz));
}

// ---------------------------------------------------------------- FPS ------
// Model (r5-r14): per-iter time ~= SUM of VMEM+LDS+VALU+tail because
// __syncthreads drains vmcnt+lgkmcnt every iteration (no overlap across the
// barrier). v7: replace the barrier with an LDS seqlock allreduce --
// leader publishes partial+flag ordered by lgkmcnt(0)-ONLY wait (global
// loads stay in flight); waves spin on flags (cheap broadcast ds_read).
// Parity-double-buffered partials are race-free: slot [J&1] is next
// overwritten at iteration J+2, which requires all waves published J+1,
// which happens after each wave's J-read of that slot.
//   - coords: blocked b128 re-stream from L1/L2 (12 float4/thread/iter)
//   - dist: LDS float4 chunks s_d[c][tid] (64KB, conflict-free b128)
//   - per-thread register state: transients only (allocator-proof)
constexpr int FT = 1024;
constexpr int FW = FT / 64;       // 16 waves

__global__ __launch_bounds__(FT) void fps_kernel(
    const float* __restrict__ xyz, float* __restrict__ centers) {
  const int b = blockIdx.x;
  const int tid = threadIdx.x;
  const int lane = tid & 63;
  const int wid = tid >> 6;
  const int l15 = lane & 15;
  const float* base = xyz + (size_t)b * N * 3;
  const float4* b4 = (const float4*)base;   // 16B-aligned

  __shared__ float4 s_d[4][FT];     // 64 KB dist (16 pts/thread, blocked)
  __shared__ float s_pv[2][FW];
  __shared__ int s_pn[2][FW];
  __shared__ int s_flag[FW];

  const float inf = __builtin_inff();
#pragma unroll
  for (int c = 0; c < 4; ++c) s_d[c][tid] = make_float4(inf, inf, inf, inf);
  if (tid < FW) s_flag[tid] = 0;

  // deterministic start: carry = point 0
  float cx = base[0], cy = base[1], cz = base[2];
  __syncthreads();   // the ONLY hard barrier (init visibility)

  const int f0 = tid * 12;   // first global float4 of this thread's 16 pts

  for (int it = 0; it < M; ++it) {
    if (tid == 0) {  // emit current carry (matches lax.scan semantics)
      float* co = centers + ((size_t)b * M + it) * 3;
      co[0] = cx; co[1] = cy; co[2] = cz;
    }
    const int p = it & 1;

    float bv = -1.0f;
    int bj = 0;

    // strict >: ascending j within thread -> lowest global idx wins ties
#define FPS_UPD(D, J, X, Y, Z) {                           \
    float dx = __fsub_rn((X), cx);                         \
    float dy = __fsub_rn((Y), cy);                         \
    float dz = __fsub_rn((Z), cz);                         \
    float dd = __fadd_rn(__fadd_rn(__fmul_rn(dx, dx),      \
                                   __fmul_rn(dy, dy)),     \
                         __fmul_rn(dz, dz));               \
    float nd = fminf(D, dd);                               \
    D = nd;                                                \
    bool g = nd > bv;                                      \
    bv = g ? nd : bv;                                      \
    bj = g ? (J) : bj; }

#pragma unroll
    for (int c = 0; c < 4; ++c) {
      float4 qa = b4[f0 + c * 3 + 0];
      float4 qb = b4[f0 + c * 3 + 1];
      float4 qc = b4[f0 + c * 3 + 2];
      float4 dq = s_d[c][tid];
      FPS_UPD(dq.x, c * 4 + 0, qa.x, qa.y, qa.z)
      FPS_UPD(dq.y, c * 4 + 1, qa.w, qb.x, qb.y)
      FPS_UPD(dq.z, c * 4 + 2, qb.z, qb.w, qc.x)
      FPS_UPD(dq.w, c * 4 + 3, qc.y, qc.z, qc.w)
      s_d[c][tid] = dq;
    }
#undef FPS_UPD

    int bn = (tid << 4) + bj;   // global point index (blocked mapping)

    // wave-level argmax, tie -> lowest global index
#pragma unroll
    for (int mm = 32; mm >= 1; mm >>= 1) {
      float ov = __shfl_xor(bv, mm, 64);
      int on = __shfl_xor(bn, mm, 64);
      if (ov > bv || (ov == bv && on < bn)) { bv = ov; bn = on; }
    }

    // leader publishes partial, then flag (LDS-ordered by lgkmcnt-only wait
    // -- global loads stay in flight, unlike __syncthreads)
    if (lane == 0) {
      s_pv[p][wid] = bv;
      s_pn[p][wid] = bn;
      asm volatile("s_waitcnt lgkmcnt(0)" ::: "memory");
      s_flag[wid] = it + 1;
    }

    // soft barrier: spin until every wave has published this iteration
    {
      volatile int* vf = s_flag;
      while (!__all(vf[l15] >= it + 1)) {}
    }
    asm volatile("" ::: "memory");  // no hoisting partial reads above spin

    // every 16-lane group holds all 16 partials -> shuffle allreduce
    float v = s_pv[p][l15];
    int n = s_pn[p][l15];
#pragma unroll
    for (int mm = 1; mm <= 8; mm <<= 1) {
      float ov = __shfl_xor(v, mm, 16);
      int on = __shfl_xor(n, mm, 16);
      if (ov > v || (ov == v && on < n)) { v = ov; n = on; }
    }
    // broadcast-load next center (uniform address -> one fetch)
    cx = base[(size_t)n * 3 + 0];
    cy = base[(size_t)n * 3 + 1];
    cz = base[(size_t)n * 3 + 2];
  }
}

// ---------------------------------------------------------------- kNN ------
// Bucket-select on float bit prefixes (monotone for d >= 0). Only the SET of
// 32 nearest matters (max-pool later), so slots are written in arbitrary
// order; boundary-bucket ties resolved exactly by (bits, index).
constexpr int KT = 256;
constexpr int CAP = 512;
constexpr int NBUCKET = 1024;

__global__ __launch_bounds__(KT) void knn_kernel(
    const float* __restrict__ xyz, const float* __restrict__ centers,
    float* __restrict__ patches) {
  const int blk = blockIdx.x;      // b*M + m
  const int b = blk >> 8;          // M == 256
  const int tid = threadIdx.x;
  const float* base = xyz + (size_t)b * N * 3;

  __shared__ int hist[NBUCKET];
  __shared__ unsigned cb[CAP];
  __shared__ int ci[CAP];
  __shared__ int s_nin, s_ncand, s_tb;
  __shared__ int s_wsum[KT / 64];
  __shared__ float s_cc[3];

  if (tid == 0) {
    const float* c = centers + (size_t)blk * 3;
    s_cc[0] = c[0]; s_cc[1] = c[1]; s_cc[2] = c[2];
    s_nin = 0; s_ncand = 0;
  }
  for (int i = tid; i < NBUCKET; i += KT) hist[i] = 0;
  __syncthreads();

  const float cx = s_cc[0], cy = s_cc[1], cz = s_cc[2];

  // pass 1: histogram of 10-bit float prefixes
  for (int n = tid; n < N; n += KT) {
    float d = sqdist(base[n * 3], base[n * 3 + 1], base[n * 3 + 2], cx, cy, cz);
    atomicAdd(&hist[__float_as_uint(d) >> 21], 1);
  }
  __syncthreads();

  // block scan over 1024 buckets (4 per thread) to find threshold bucket
  int h0[4];
  int loc = 0;
#pragma unroll
  for (int i = 0; i < 4; ++i) { h0[i] = hist[tid * 4 + i]; loc += h0[i]; }
  int lane = tid & 63, wid = tid >> 6;
  int scan = loc;
  for (int off = 1; off < 64; off <<= 1) {
    int o = __shfl_up(scan, off, 64);
    if (lane >= off) scan += o;
  }
  if (lane == 63) s_wsum[wid] = scan;
  __syncthreads();
  int woff = 0;
  for (int w = 0; w < wid; ++w) woff += s_wsum[w];
  int c0 = woff + scan - loc;  // count strictly below this thread's buckets
#pragma unroll
  for (int i = 0; i < 4; ++i) {
    int c1 = c0 + h0[i];
    if (c0 < K && c1 >= K) s_tb = tid * 4 + i;  // unique crossing bucket
    c0 = c1;
  }
  __syncthreads();
  const int tb = s_tb;
  const unsigned lo = (unsigned)tb << 21;
  const unsigned hi = (unsigned)(tb + 1) << 21;

  // pass 2: emit sure-ins, collect boundary candidates
  for (int n = tid; n < N; n += KT) {
    float x = base[n * 3], y = base[n * 3 + 1], z = base[n * 3 + 2];
    float d = sqdist(x, y, z, cx, cy, cz);
    unsigned bits = __float_as_uint(d);
    if (bits < lo) {
      int pos = atomicAdd(&s_nin, 1);
      float* p = patches + ((size_t)blk * K + pos) * 3;
      p[0] = __fsub_rn(x, cx); p[1] = __fsub_rn(y, cy); p[2] = __fsub_rn(z, cz);
    } else if (bits < hi) {
      int q = atomicAdd(&s_ncand, 1);
      if (q < CAP) { cb[q] = bits; ci[q] = n; }
    }
  }
  __syncthreads();

  // exact rank-select among boundary candidates: (bits, idx) lexicographic
  const int nin = s_nin;
  const int ncand = min(s_ncand, CAP);
  const int nsel = K - nin;
  for (int j = tid; j < ncand; j += KT) {
    unsigned bj = cb[j];
    int ij = ci[j];
    int rank = 0;
    for (int i2 = 0; i2 < ncand; ++i2) {
      unsigned bv = cb[i2];
      int iv = ci[i2];
      rank += (bv < bj || (bv == bj && iv < ij)) ? 1 : 0;
    }
    if (rank < nsel) {
      float x = base[ij * 3], y = base[ij * 3 + 1], z = base[ij * 3 + 2];
      float* p = patches + ((size_t)blk * K + nin + rank) * 3;
      p[0] = __fsub_rn(x, cx); p[1] = __fsub_rn(y, cy); p[2] = __fsub_rn(z, cz);
    }
  }
}

// ---------------------------------------------------------------- MLP ------
// One block per patch. h1/h2 staged in LDS, rows XOR-swizzled so the b128
// writes are conflict-light; reads are uniform-address broadcasts.
constexpr int MT = 128;

__global__ __launch_bounds__(MT) void mlp_kernel(
    const float* __restrict__ patches,
    const float* __restrict__ W1, const float* __restrict__ b1,
    const float* __restrict__ g1, const float* __restrict__ bt1,
    const float* __restrict__ W2, const float* __restrict__ b2,
    const float* __restrict__ g2, const float* __restrict__ bt2,
    const float* __restrict__ W3, const float* __restrict__ b3,
    const float* __restrict__ g3, const float* __restrict__ bt3,
    float* __restrict__ tokens) {
  const int pm = blockIdx.x;
  const int tid = threadIdx.x;
  __shared__ float xs[3][K];
  __shared__ float h1s[64 * K];
  __shared__ float h2s[128 * K];
  __shared__ float pms[2][EMB];

  const float* patch = patches + (size_t)pm * (K * 3);
  if (tid < 96) xs[tid % 3][tid / 3] = patch[tid];
  __syncthreads();

  const int cg = tid & 63;
  const int half = tid >> 6;
  const int pt0 = half * 16;
  const float rs = 1.0f / sqrtf(1.0f + 1e-5f);

  // L1: 3 -> 64
  {
    const int c = cg;
    const float w0 = W1[c], w1 = W1[64 + c], w2 = W1[128 + c];
    const float bb = b1[c];
    const float sc = g1[c] * rs, be = bt1[c];
    float o[16];
#pragma unroll
    for (int p = 0; p < 16; ++p) {
      int pt = pt0 + p;
      float a = xs[0][pt] * w0 + xs[1][pt] * w1 + xs[2][pt] * w2 + bb;
      o[p] = fmaxf(a * sc + be, 0.0f);
    }
    const int so = (c & 7) << 2;
#pragma unroll
    for (int p4 = 0; p4 < 16; p4 += 4) {
      *(float4*)&h1s[c * K + ((pt0 + p4) ^ so)] =
          make_float4(o[p4], o[p4 + 1], o[p4 + 2], o[p4 + 3]);
    }
  }
  __syncthreads();

  // L2: 64 -> 128, c-tile 2 x pt-tile 16
  {
    const int c = cg * 2;
    float acc0[16], acc1[16];
    const float bb0 = b2[c], bb1 = b2[c + 1];
#pragma unroll
    for (int p = 0; p < 16; ++p) { acc0[p] = bb0; acc1[p] = bb1; }
    for (int k = 0; k < 64; ++k) {
      const float2 w = *(const float2*)(W2 + k * 128 + c);
      const int so = (k & 7) << 2;
      float4 x0 = *(const float4*)&h1s[k * K + ((pt0 + 0) ^ so)];
      float4 x1 = *(const float4*)&h1s[k * K + ((pt0 + 4) ^ so)];
      float4 x2 = *(const float4*)&h1s[k * K + ((pt0 + 8) ^ so)];
      float4 x3 = *(const float4*)&h1s[k * K + ((pt0 + 12) ^ so)];
      float xv[16] = {x0.x, x0.y, x0.z, x0.w, x1.x, x1.y, x1.z, x1.w,
                      x2.x, x2.y, x2.z, x2.w, x3.x, x3.y, x3.z, x3.w};
#pragma unroll
      for (int p = 0; p < 16; ++p) {
        acc0[p] += xv[p] * w.x;
        acc1[p] += xv[p] * w.y;
      }
    }
    const float sc0 = g2[c] * rs, be0 = bt2[c];
    const float sc1 = g2[c + 1] * rs, be1 = bt2[c + 1];
    float o0[16], o1[16];
#pragma unroll
    for (int p = 0; p < 16; ++p) {
      o0[p] = fmaxf(acc0[p] * sc0 + be0, 0.0f);
      o1[p] = fmaxf(acc1[p] * sc1 + be1, 0.0f);
    }
    const int soa = (c & 7) << 2, sob = ((c + 1) & 7) << 2;
#pragma unroll
    for (int p4 = 0; p4 < 16; p4 += 4) {
      *(float4*)&h2s[c * K + ((pt0 + p4) ^ soa)] =
          make_float4(o0[p4], o0[p4 + 1], o0[p4 + 2], o0[p4 + 3]);
      *(float4*)&h2s[(c + 1) * K + ((pt0 + p4) ^ sob)] =
          make_float4(o1[p4], o1[p4 + 1], o1[p4 + 2], o1[p4 + 3]);
    }
  }
  __syncthreads();

  // L3: 128 -> 256, c-tile 4 x pt-tile 16, fused BN+ReLU+max over its pts
  {
    const int c = cg * 4;
    float acc[4][16];
#pragma unroll
    for (int i = 0; i < 4; ++i) {
      const float bb = b3[c + i];
#pragma unroll
      for (int p = 0; p < 16; ++p) acc[i][p] = bb;
    }
    for (int k = 0; k < 128; ++k) {
      const float4 w = *(const float4*)(W3 + (size_t)k * 256 + c);
      const int so = (k & 7) << 2;
      float4 x0 = *(const float4*)&h2s[k * K + ((pt0 + 0) ^ so)];
      float4 x1 = *(const float4*)&h2s[k * K + ((pt0 + 4) ^ so)];
      float4 x2 = *(const float4*)&h2s[k * K + ((pt0 + 8) ^ so)];
      float4 x3 = *(const float4*)&h2s[k * K + ((pt0 + 12) ^ so)];
      float xv[16] = {x0.x, x0.y, x0.z, x0.w, x1.x, x1.y, x1.z, x1.w,
                      x2.x, x2.y, x2.z, x2.w, x3.x, x3.y, x3.z, x3.w};
#pragma unroll
      for (int p = 0; p < 16; ++p) {
        acc[0][p] += xv[p] * w.x;
        acc[1][p] += xv[p] * w.y;
        acc[2][p] += xv[p] * w.z;
        acc[3][p] += xv[p] * w.w;
      }
    }
#pragma unroll
    for (int i = 0; i < 4; ++i) {
      const float sc = g3[c + i] * rs, be = bt3[c + i];
      float mx = 0.0f;  // ReLU outputs are >= 0, so 0 is a safe identity
#pragma unroll
      for (int p = 0; p < 16; ++p)
        mx = fmaxf(mx, fmaxf(acc[i][p] * sc + be, 0.0f));
      pms[half][c + i] = mx;
    }
  }
  __syncthreads();

  {
    const int c2 = tid * 2;
    float* to = tokens + (size_t)pm * EMB;
    to[c2] = fmaxf(pms[0][c2], pms[1][c2]);
    to[c2 + 1] = fmaxf(pms[0][c2 + 1], pms[1][c2 + 1]);
  }
}

// ------------------------------------------------------------- launcher ----
extern "C" void kernel_launch(void* const* d_in, const int* in_sizes, int n_in,
                              void* d_out, int out_size, void* d_ws,
                              size_t ws_size, hipStream_t stream) {
  const float* xyz = (const float*)d_in[0];
  const float* W1 = (const float*)d_in[1];
  const float* b1 = (const float*)d_in[2];
  const float* g1 = (const float*)d_in[3];
  const float* bt1 = (const float*)d_in[4];
  const float* W2 = (const float*)d_in[5];
  const float* b2 = (const float*)d_in[6];
  const float* g2 = (const float*)d_in[7];
  const float* bt2 = (const float*)d_in[8];
  const float* W3 = (const float*)d_in[9];
  const float* b3 = (const float*)d_in[10];
  const float* g3 = (const float*)d_in[11];
  const float* bt3 = (const float*)d_in[12];

  float* tokens = (float*)d_out;                       // (B,M,EMB)
  float* centers = tokens + (size_t)B * M * EMB;       // (B,M,3)
  float* patches = (float*)d_ws;                       // (B*M, K, 3)

  fps_kernel<<<B, FT, 0, stream>>>(xyz, centers);
  knn_kernel<<<B * M, KT, 0, stream>>>(xyz, centers, patches);
  mlp_kernel<<<B * M, MT, 0, stream>>>(patches, W1, b1, g1, bt1, W2, b2, g2,
                                       bt2, W3, b3, g3, bt3, tokens);
}